// Round 10
// baseline (268.903 us; speedup 1.0000x reference)
//
#include <hip/hip_runtime.h>
#include <hip/hip_bf16.h>
#include <hip/hip_cooperative_groups.h>
#include <math.h>

namespace cg = cooperative_groups;

constexpr int BB = 2;
constexpr int TT = 2048;
constexpr int EE = 1024;
constexpr int HH = 16;
constexpr int DD = 64;

typedef __bf16 v8bf __attribute__((ext_vector_type(8)));
typedef __bf16 v4bf __attribute__((ext_vector_type(4)));
typedef short  v4s  __attribute__((ext_vector_type(4)));
typedef float  v4f  __attribute__((ext_vector_type(4)));

#define MFMA16(a, b, c) __builtin_amdgcn_mfma_f32_16x16x32_bf16(a, b, c, 0, 0, 0)
#define MFMA16K16(a, b, c) __builtin_amdgcn_mfma_f32_16x16x16bf16_1k(a, b, c, 0, 0, 0)

// ---------------------------------------------------------------------------
// GEMM phase: C[4096,1024] = A[4096,1024] @ Bw[1024,1024]^T + bias
// 128x128 tile, BK=32, 8 waves (2x4 of 64x32). 256 blocks, XCD swizzle.
// VGPR-staged (fp32->bf16 cvt folded), reg double buffer, 1 barrier/iter,
// XOR chunk swizzle on LDS side (global reads stay straight/coalesced).
// AFP32: A is fp32 (cvt) vs bf16.  MODE 0: C fp32; MODE 1: C bf16 vxT scatter.
// ---------------------------------------------------------------------------
template <bool AFP32, int MODE>
__device__ __forceinline__ void gemm_phase(
    const void* __restrict__ Ap, const float* __restrict__ Bw,
    const float* __restrict__ bias, void* __restrict__ Cout,
    unsigned char* smem)
{
    constexpr int K = EE;
    auto Ah = (__bf16 (*)[128][32])(smem);           // [2][128][32]
    auto Bh = (__bf16 (*)[128][32])(smem + 16384);   // [2][128][32]

    const int tid = threadIdx.x;
    const int w = tid >> 6, lane = tid & 63, quad = lane >> 4, l15 = lane & 15;
    const int bid = blockIdx.x;
    const int xcd = bid & 7, slot = bid >> 3;
    const int bx = (xcd & 1) * 4 + (slot & 3);     // n-tile 0..7
    const int by = (xcd >> 1) * 8 + (slot >> 2);   // m-tile 0..31
    const int m0 = by * 128, n0 = bx * 128;
    const int wm = (w >> 2) * 64, wn = (w & 3) * 32;

    const int srow = 16 * w + (lane >> 2);                  // staged row 0..127
    const int scl  = (lane & 3) * 8;                        // global col in BK
    const int spc  = ((lane & 3) ^ ((srow >> 1) & 3)) * 8;  // swizzled LDS col

    const float*  Af = (const float*)Ap;
    const __bf16* Ab = (const __bf16*)Ap;

    v4f acc[4][2] = {};
    float bn[2];
    #pragma unroll
    for (int ns = 0; ns < 2; ++ns) bn[ns] = bias[n0 + wn + ns * 16 + l15];

    float4 fa0, fa1, fb0, fb1;
    uint4 ua;

    auto loadT = [&](int i) {
        const int k0 = i * 32;
        if (AFP32) {
            const float* p = Af + (size_t)(m0 + srow) * K + k0 + scl;
            fa0 = ((const float4*)p)[0]; fa1 = ((const float4*)p)[1];
        } else {
            ua = *(const uint4*)(Ab + (size_t)(m0 + srow) * K + k0 + scl);
        }
        const float* p = Bw + (size_t)(n0 + srow) * K + k0 + scl;
        fb0 = ((const float4*)p)[0]; fb1 = ((const float4*)p)[1];
    };
    auto writeT = [&](int pb) {
        v8bf va, vb2;
        if (AFP32) {
            float f[8] = {fa0.x, fa0.y, fa0.z, fa0.w, fa1.x, fa1.y, fa1.z, fa1.w};
            #pragma unroll
            for (int j = 0; j < 8; ++j) va[j] = (__bf16)f[j];
        } else {
            va = *(v8bf*)&ua;
        }
        float f[8] = {fb0.x, fb0.y, fb0.z, fb0.w, fb1.x, fb1.y, fb1.z, fb1.w};
        #pragma unroll
        for (int j = 0; j < 8; ++j) vb2[j] = (__bf16)f[j];
        *(v8bf*)&Ah[pb][srow][spc] = va;
        *(v8bf*)&Bh[pb][srow][spc] = vb2;
    };

    loadT(0);
    writeT(0);
    __syncthreads();

    const int NIT = K / 32;
    for (int i = 0; i < NIT; ++i) {
        const int p = i & 1;
        if (i + 1 < NIT) loadT(i + 1);          // global loads in flight
        v8bf af[4], bf2[2];
        #pragma unroll
        for (int ms = 0; ms < 4; ++ms) {
            const int r = wm + ms * 16 + l15;
            af[ms] = *(const v8bf*)&Ah[p][r][(quad ^ ((r >> 1) & 3)) * 8];
        }
        #pragma unroll
        for (int ns = 0; ns < 2; ++ns) {
            const int r = wn + ns * 16 + l15;
            bf2[ns] = *(const v8bf*)&Bh[p][r][(quad ^ ((r >> 1) & 3)) * 8];
        }
        #pragma unroll
        for (int ms = 0; ms < 4; ++ms)
            #pragma unroll
            for (int ns = 0; ns < 2; ++ns)
                acc[ms][ns] = MFMA16(af[ms], bf2[ns], acc[ms][ns]);
        if (i + 1 < NIT) writeT(1 - p);          // cvt + store to other buffer
        __syncthreads();
    }

    #pragma unroll
    for (int ms = 0; ms < 4; ++ms) {
        const int mbase = m0 + wm + ms * 16 + quad * 4;
        #pragma unroll
        for (int ns = 0; ns < 2; ++ns) {
            const int n = n0 + wn + ns * 16 + l15;
            if (MODE == 0) {
                float* C = (float*)Cout;
                #pragma unroll
                for (int r = 0; r < 4; ++r)
                    C[(size_t)(mbase + r) * EE + n] = acc[ms][ns][r] + bn[ns];
            } else {
                const int bq = mbase >> 11, t = mbase & 2047;
                const int hh = n >> 6, dd = n & 63;
                v4bf pk;
                #pragma unroll
                for (int r = 0; r < 4; ++r) pk[r] = (__bf16)(acc[ms][ns][r] + bn[ns]);
                *(v4bf*)((__bf16*)Cout + (((size_t)bq * HH + hh) * DD + dd) * TT + t) = pk;
            }
        }
    }
}

// ---------------------------------------------------------------------------
// Attention phase: block = (b, h, 256-q-row strip), 8 waves x 32 q-rows.
// All 8 waves share one 64-row K/V tile per s-iter (staging per q-row halved
// vs R9). Max-free softmax, P in registers via S^T = K*Q^T. K cvt'd from
// fp32 x during staging. 256 blocks = 2*16*8 strips.
// ---------------------------------------------------------------------------
__device__ __forceinline__ void attn_phase(
    const float* __restrict__ x, const float* __restrict__ watt,
    const __bf16* __restrict__ vxT, __bf16* __restrict__ o,
    unsigned char* smem)
{
    auto Khi = (__bf16 (*)[72])(smem);           // [64][72]
    auto Vt  = (__bf16 (*)[72])(smem + 9216);    // [64][72]
    auto Pm  = (__bf16 (*)[72])(smem + 18432);   // [128][72]
    auto Xlo = (__bf16 (*)[72])(smem + 36864);   // [128][72]

    const int tid = threadIdx.x;
    const int w = tid >> 6, lane = tid & 63, quad = lane >> 4, l15 = lane & 15;
    const int bid = blockIdx.x;
    const int c = bid & 31, strip = bid >> 5;    // same-(b,h) strips share XCD
    const int b = c >> 4, h = c & 15;
    const int t0 = strip * 256;

    // ---- W_h^T staging (scaled, hi/lo), once ----
    {
        const int r = tid >> 3, c0 = (tid & 7) * 8;
        const float* wp = watt + ((size_t)h * DD + r) * DD + c0;
        #pragma unroll
        for (int i = 0; i < 8; ++i) {
            const float f = wp[i] * 0.125f;      // fold 1/sqrt(D)
            __bf16 hv = (__bf16)f;
            Khi[c0 + i][r] = hv;
            Vt[c0 + i][r]  = (__bf16)(f - (float)hv);
        }
    }

    // ---- Q = X W_h (split-3), two 128-row passes; wave w owns rows 32w..32w+32
    v8bf qh[2][2], ql[2][2];
    for (int pp = 0; pp < 2; ++pp) {
        __syncthreads();  // W staged / prior pass's Pm readers done
        {
            const int row = tid >> 2, q4 = (tid & 3) * 16;
            const float* xp = x + ((size_t)(b * TT + t0 + pp * 128 + row)) * EE + h * DD + q4;
            #pragma unroll
            for (int cc = 0; cc < 2; ++cc) {
                float4 f0 = ((const float4*)xp)[cc * 2];
                float4 f1 = ((const float4*)xp)[cc * 2 + 1];
                float f[8] = {f0.x, f0.y, f0.z, f0.w, f1.x, f1.y, f1.z, f1.w};
                v8bf hi, lo;
                #pragma unroll
                for (int j = 0; j < 8; ++j) {
                    __bf16 hv = (__bf16)f[j];
                    hi[j] = hv;
                    lo[j] = (__bf16)(f[j] - (float)hv);
                }
                *(v8bf*)&Pm[row][q4 + cc * 8] = hi;
                *(v8bf*)&Xlo[row][q4 + cc * 8] = lo;
            }
        }
        __syncthreads();
        v4f qacc[2][4] = {};
        const int wl = w & 3;
        if ((w >> 2) == pp) {
            #pragma unroll
            for (int kk = 0; kk < 2; ++kk) {
                v8bf xhf[2], xlf[2];
                #pragma unroll
                for (int mr = 0; mr < 2; ++mr) {
                    xhf[mr] = *(const v8bf*)&Pm[wl * 32 + mr * 16 + l15][kk * 32 + quad * 8];
                    xlf[mr] = *(const v8bf*)&Xlo[wl * 32 + mr * 16 + l15][kk * 32 + quad * 8];
                }
                #pragma unroll
                for (int ns = 0; ns < 4; ++ns) {
                    v8bf wh = *(const v8bf*)&Khi[ns * 16 + l15][kk * 32 + quad * 8];
                    v8bf wl2 = *(const v8bf*)&Vt[ns * 16 + l15][kk * 32 + quad * 8];
                    #pragma unroll
                    for (int mr = 0; mr < 2; ++mr) {
                        qacc[mr][ns] = MFMA16(xlf[mr], wh, qacc[mr][ns]);
                        qacc[mr][ns] = MFMA16(xhf[mr], wl2, qacc[mr][ns]);
                        qacc[mr][ns] = MFMA16(xhf[mr], wh, qacc[mr][ns]);
                    }
                }
            }
        }
        __syncthreads();  // all X/W reads of this pass done
        if ((w >> 2) == pp) {
            // scatter Q hi/lo into wave-local rows, reload as frags (wave-local,
            // in-order ds ops -> no barrier needed before reload)
            #pragma unroll
            for (int mr = 0; mr < 2; ++mr)
                #pragma unroll
                for (int ns = 0; ns < 4; ++ns)
                    #pragma unroll
                    for (int r = 0; r < 4; ++r) {
                        const float f = qacc[mr][ns][r];
                        __bf16 hv = (__bf16)f;
                        Pm[wl * 32 + mr * 16 + quad * 4 + r][ns * 16 + l15] = hv;
                        Xlo[wl * 32 + mr * 16 + quad * 4 + r][ns * 16 + l15] = (__bf16)(f - (float)hv);
                    }
            #pragma unroll
            for (int mr = 0; mr < 2; ++mr)
                #pragma unroll
                for (int kk = 0; kk < 2; ++kk) {
                    qh[mr][kk] = *(const v8bf*)&Pm[wl * 32 + mr * 16 + l15][kk * 32 + quad * 8];
                    ql[mr][kk] = *(const v8bf*)&Xlo[wl * 32 + mr * 16 + l15][kk * 32 + quad * 8];
                }
        }
    }

    v4f oacc[2][4] = {};
    float ll[2] = {0.f, 0.f};
    const __bf16* vb = vxT + ((size_t)(b * HH + h)) * DD * TT;
    const int kr = tid >> 3, kc = (tid & 7) * 8;

    // ---- main loop over 64-row s-tiles (shared by all 8 waves) ----
    for (int s0 = 0; s0 < TT; s0 += 64) {
        const float* kp = x + ((size_t)(b * TT + s0 + kr)) * EE + h * DD + kc;
        float4 k0 = ((const float4*)kp)[0];
        float4 k1 = ((const float4*)kp)[1];
        uint4 vv = *(const uint4*)(vb + (size_t)kr * TT + s0 + kc);
        __syncthreads();  // prior iteration's K/V readers done
        {
            float f[8] = {k0.x, k0.y, k0.z, k0.w, k1.x, k1.y, k1.z, k1.w};
            v8bf kb8;
            #pragma unroll
            for (int j = 0; j < 8; ++j) kb8[j] = (__bf16)f[j];
            *(v8bf*)&Khi[kr][kc] = kb8;
            *(uint4*)&Vt[kr][kc] = vv;
        }
        __syncthreads();

        // S^T = K (Q_hi + Q_lo)^T : K-frag read once, reused 4x
        v4f sacc[2][4] = {};
        #pragma unroll
        for (int kk = 0; kk < 2; ++kk)
            #pragma unroll
            for (int ss = 0; ss < 4; ++ss) {
                v8bf kf = *(const v8bf*)&Khi[ss * 16 + l15][kk * 32 + quad * 8];
                #pragma unroll
                for (int mr = 0; mr < 2; ++mr) {
                    sacc[mr][ss] = MFMA16(kf, ql[mr][kk], sacc[mr][ss]);
                    sacc[mr][ss] = MFMA16(kf, qh[mr][kk], sacc[mr][ss]);
                }
            }

        // exp in-place; pack to bf16 A-frags; l per lane
        v4s pa[2][4];
        #pragma unroll
        for (int mr = 0; mr < 2; ++mr)
            #pragma unroll
            for (int ss = 0; ss < 4; ++ss) {
                v4bf pb;
                #pragma unroll
                for (int r = 0; r < 4; ++r) {
                    const float p = __expf(sacc[mr][ss][r]);
                    ll[mr] += p;
                    pb[r] = (__bf16)p;
                }
                union { v4bf b; v4s s; } u;
                u.b = pb;
                pa[mr][ss] = u.s;
            }

        // O += P V : V-frag read once, reused 2x
        #pragma unroll
        for (int ss = 0; ss < 4; ++ss)
            #pragma unroll
            for (int ds = 0; ds < 4; ++ds) {
                v4s vf = *(const v4s*)&Vt[ds * 16 + l15][ss * 16 + quad * 4];
                #pragma unroll
                for (int mr = 0; mr < 2; ++mr)
                    oacc[mr][ds] = MFMA16K16(pa[mr][ss], vf, oacc[mr][ds]);
            }
    }

    // ---- epilogue: total l per q, store O/l ----
    #pragma unroll
    for (int mr = 0; mr < 2; ++mr) {
        float s = ll[mr];
        s += __shfl_xor(s, 16);
        s += __shfl_xor(s, 32);
        float inv[4];
        #pragma unroll
        for (int r = 0; r < 4; ++r)
            inv[r] = 1.0f / __shfl(s, quad * 4 + r);
        #pragma unroll
        for (int ds = 0; ds < 4; ++ds)
            #pragma unroll
            for (int r = 0; r < 4; ++r) {
                const float val = oacc[mr][ds][r] * inv[r];
                o[(size_t)(b * TT + t0 + w * 32 + mr * 16 + quad * 4 + r) * EE +
                  h * DD + ds * 16 + l15] = (__bf16)val;
            }
    }
}

// ---------------------------------------------------------------------------
// Mega kernel: gemm1 -> grid.sync -> attn -> grid.sync -> gemm2.
// 256 blocks x 512 threads, 55.3 KB LDS -> guaranteed co-resident.
// ---------------------------------------------------------------------------
__global__ void __launch_bounds__(512, 1) mega(
    const float* __restrict__ x, const float* __restrict__ watt,
    const float* __restrict__ wv_w, const float* __restrict__ wv_b,
    const float* __restrict__ out_w, const float* __restrict__ out_b,
    float* __restrict__ out, __bf16* __restrict__ vxT, __bf16* __restrict__ obf)
{
    __shared__ __align__(16) unsigned char smem[55296];
    cg::grid_group grid = cg::this_grid();

    // vx = x @ wv_w^T + wv_b  -> vxT (B,H,D,T) bf16
    gemm_phase<true, 1>(x, wv_w, wv_b, (void*)vxT, smem);
    grid.sync();
    // fused bilinear attention -> obf (B,T,E) bf16
    attn_phase(x, watt, vxT, obf, smem);
    grid.sync();
    // out = o @ out_w^T + out_b (fp32)
    gemm_phase<false, 0>(obf, out_w, out_b, (void*)out, smem);
}

// ---------------------------------------------------------------------------
extern "C" void kernel_launch(void* const* d_in, const int* in_sizes, int n_in,
                              void* d_out, int out_size, void* d_ws, size_t ws_size,
                              hipStream_t stream)
{
    const float* x     = (const float*)d_in[0];
    const float* watt  = (const float*)d_in[1];
    const float* wv_w  = (const float*)d_in[2];
    const float* wv_b  = (const float*)d_in[3];
    const float* out_w = (const float*)d_in[4];
    const float* out_b = (const float*)d_in[5];
    float* out = (float*)d_out;

    __bf16* vxT = (__bf16*)d_ws;                      // B*H*D*T bf16
    __bf16* obf = vxT + (size_t)BB * HH * DD * TT;    // B*T*E bf16

    void* args[] = {
        (void*)&x, (void*)&watt, (void*)&wv_w, (void*)&wv_b,
        (void*)&out_w, (void*)&out_b, (void*)&out, (void*)&vxT, (void*)&obf
    };
    hipLaunchCooperativeKernel((const void*)mega, dim3(256), dim3(512),
                               args, 0, stream);
}

// Round 11
// 174.682 us; speedup vs baseline: 1.5394x; 1.5394x over previous
//
#include <hip/hip_runtime.h>
#include <hip/hip_bf16.h>
#include <math.h>

constexpr int BB = 2;
constexpr int TT = 2048;
constexpr int EE = 1024;
constexpr int HH = 16;
constexpr int DD = 64;

typedef __bf16 v8bf __attribute__((ext_vector_type(8)));
typedef __bf16 v4bf __attribute__((ext_vector_type(4)));
typedef short  v4s  __attribute__((ext_vector_type(4)));
typedef float  v4f  __attribute__((ext_vector_type(4)));

#define MFMA16(a, b, c) __builtin_amdgcn_mfma_f32_16x16x32_bf16(a, b, c, 0, 0, 0)
#define MFMA16K16(a, b, c) __builtin_amdgcn_mfma_f32_16x16x16bf16_1k(a, b, c, 0, 0, 0)

// async global -> LDS, 16 B per lane; LDS dest = wave-uniform base + lane*16
__device__ __forceinline__ void gll16(const void* g, void* l) {
    __builtin_amdgcn_global_load_lds(
        (const __attribute__((address_space(1))) unsigned int*)g,
        (__attribute__((address_space(3))) unsigned int*)(unsigned)(uintptr_t)l,
        16, 0, 0);
}

// ---------------------------------------------------------------------------
// cast_all: x -> x_hi (bf16), wv_w -> bf16, out_w -> bf16.  8 elems/thread.
// ---------------------------------------------------------------------------
__global__ __launch_bounds__(256) void cast_all(
    const float* __restrict__ x, const float* __restrict__ wv,
    const float* __restrict__ ow,
    __bf16* __restrict__ xhi, __bf16* __restrict__ wvb, __bf16* __restrict__ owb)
{
    const int bid = blockIdx.x;
    const float* src;
    __bf16* dst;
    int base;
    if (bid < 2048)      { src = x;  dst = xhi; base = bid; }
    else if (bid < 2560) { src = wv; dst = wvb; base = bid - 2048; }
    else                 { src = ow; dst = owb; base = bid - 2560; }
    const size_t i = (size_t)base * 256 + threadIdx.x;
    float4 f0 = ((const float4*)src)[i * 2];
    float4 f1 = ((const float4*)src)[i * 2 + 1];
    float f[8] = {f0.x, f0.y, f0.z, f0.w, f1.x, f1.y, f1.z, f1.w};
    v8bf h;
    #pragma unroll
    for (int j = 0; j < 8; ++j) h[j] = (__bf16)f[j];
    *(v8bf*)(dst + i * 8) = h;
}

// ---------------------------------------------------------------------------
// bf16 MFMA GEMM (R9 proven): 128x128, BK=32, 512 thr, XCD swizzle, gll16,
// XOR chunk swizzle, depth-1 double buffer, one barrier per K-iter.
// MODE 0: C fp32 row-major; MODE 1: C bf16 as vxT (B,H,D,T)
// ---------------------------------------------------------------------------
template <int MODE>
__global__ __launch_bounds__(512) void gemm_bf16(
    const __bf16* __restrict__ A, const __bf16* __restrict__ Bw,
    const float* __restrict__ bias, void* __restrict__ Cout,
    int M, int N, int K)
{
    __shared__ __bf16 Ah[2][128][32];
    __shared__ __bf16 Bh[2][128][32];

    const int tid = threadIdx.x;
    const int w = tid >> 6, lane = tid & 63, quad = lane >> 4, l15 = lane & 15;
    const int bid = blockIdx.x;
    const int xcd = bid & 7, slot = bid >> 3;
    const int bx = (xcd & 1) * 4 + (slot & 3);     // n-tile 0..7
    const int by = (xcd >> 1) * 8 + (slot >> 2);   // m-tile 0..31
    const int m0 = by * 128, n0 = bx * 128;
    const int wm = (w >> 2) * 64, wn = (w & 3) * 32;

    v4f acc[4][2] = {};
    float bn[2];
    #pragma unroll
    for (int ns = 0; ns < 2; ++ns) bn[ns] = bias[n0 + wn + ns * 16 + l15];

    const int srow = 16 * w + (lane >> 2);
    const int clog = (lane & 3) ^ ((srow >> 1) & 3);
    const __bf16* ag = A + (size_t)(m0 + srow) * K + clog * 8;
    const __bf16* bg = Bw + (size_t)(n0 + srow) * K + clog * 8;

    gll16(ag, &Ah[0][16 * w][0]);
    gll16(bg, &Bh[0][16 * w][0]);
    __syncthreads();

    const int NIT = K / 32;
    for (int i = 0; i < NIT; ++i) {
        const int p = i & 1;
        if (i + 1 < NIT) {
            const size_t ko = (size_t)(i + 1) * 32;
            gll16(ag + ko, &Ah[1 - p][16 * w][0]);
            gll16(bg + ko, &Bh[1 - p][16 * w][0]);
        }
        v8bf af[4], bf2[2];
        #pragma unroll
        for (int ms = 0; ms < 4; ++ms) {
            const int r = wm + ms * 16 + l15;
            af[ms] = *(const v8bf*)&Ah[p][r][(quad ^ ((r >> 1) & 3)) * 8];
        }
        #pragma unroll
        for (int ns = 0; ns < 2; ++ns) {
            const int r = wn + ns * 16 + l15;
            bf2[ns] = *(const v8bf*)&Bh[p][r][(quad ^ ((r >> 1) & 3)) * 8];
        }
        #pragma unroll
        for (int ms = 0; ms < 4; ++ms)
            #pragma unroll
            for (int ns = 0; ns < 2; ++ns)
                acc[ms][ns] = MFMA16(af[ms], bf2[ns], acc[ms][ns]);
        __syncthreads();
    }

    #pragma unroll
    for (int ms = 0; ms < 4; ++ms) {
        const int mbase = m0 + wm + ms * 16 + quad * 4;
        #pragma unroll
        for (int ns = 0; ns < 2; ++ns) {
            const int n = n0 + wn + ns * 16 + l15;
            if (MODE == 0) {
                float* C = (float*)Cout;
                #pragma unroll
                for (int r = 0; r < 4; ++r)
                    C[(size_t)(mbase + r) * N + n] = acc[ms][ns][r] + bn[ns];
            } else {
                const int bq = mbase >> 11, t = mbase & 2047;
                const int hh = n >> 6, dd = n & 63;
                v4bf pk;
                #pragma unroll
                for (int r = 0; r < 4; ++r) pk[r] = (__bf16)(acc[ms][ns][r] + bn[ns]);
                *(v4bf*)((__bf16*)Cout + (((size_t)bq * HH + hh) * DD + dd) * TT + t) = pk;
            }
        }
    }
}

// ---------------------------------------------------------------------------
// MFMA flash attention, single-barrier pipelined K-loop.
// Block = (b, h, 128 q-rows), 4 waves x 32 q-rows.  Max-free softmax
// (exp2, log2e*0.125 folded into W), P in registers via S^T = K*Q^T,
// l via ones-column MFMA (lands in oacc layout -> no epilogue shuffles).
// K/V double-buffered in LDS: KV0/KV1 [128][72] (K rows 0-63, V rows 64-127);
// per iter: prefetch regs (i+2), compute buf, write regs(i+1)->other buf,
// ONE __syncthreads.  LDS 55.3 KB -> 2 blocks/CU, grid 512 = all resident.
// ---------------------------------------------------------------------------
__global__ __launch_bounds__(256, 2) void attn_mfma(
    const float* __restrict__ x,      // (B,T,E) fp32 (phase-0 Q input)
    const __bf16* __restrict__ xh,    // (B,T,E) bf16 (K)
    const float* __restrict__ watt,   // (H,D,D) fp32
    const __bf16* __restrict__ vxT,   // (B,H,D,T) bf16
    __bf16* __restrict__ o)           // (B,T,E) bf16
{
    constexpr int LDP = 72;
    __shared__ __bf16 KV0[128][LDP];  // ph0: X_hi / Q_hi ; loop: buffer 0
    __shared__ __bf16 KV1[128][LDP];  // ph0: X_lo / Q_lo ; loop: buffer 1
    __shared__ __bf16 Wh[64][LDP];    // W_h^T hi (scaled)
    __shared__ __bf16 Wl[64][LDP];    // W_h^T lo

    const int tid = threadIdx.x;
    const int w = tid >> 6, lane = tid & 63, quad = lane >> 4, l15 = lane & 15;
    const int qt = blockIdx.x, h = blockIdx.y, b = blockIdx.z;
    const int t0 = qt * 128;

    // scale: 1/sqrt(D) * log2(e)  (scores computed in log2 domain -> exp2)
    const float WSC = 0.125f * 1.4426950408889634f;

    // ---- phase 0: stage X q-tile (fp32 -> hi/lo) and W_h^T (scaled, hi/lo)
    {
        const int row = tid >> 1, half = (tid & 1) * 32;
        const float* xp = x + ((size_t)(b * TT + t0 + row)) * EE + h * DD + half;
        #pragma unroll
        for (int c = 0; c < 4; ++c) {
            float4 f0 = ((const float4*)xp)[c * 2];
            float4 f1 = ((const float4*)xp)[c * 2 + 1];
            float f[8] = {f0.x, f0.y, f0.z, f0.w, f1.x, f1.y, f1.z, f1.w};
            v8bf hi, lo;
            #pragma unroll
            for (int j = 0; j < 8; ++j) {
                __bf16 hv = (__bf16)f[j];
                hi[j] = hv;
                lo[j] = (__bf16)(f[j] - (float)hv);
            }
            *(v8bf*)&KV0[row][half + c * 8] = hi;
            *(v8bf*)&KV1[row][half + c * 8] = lo;
        }
        const int r = tid >> 2, c0 = (tid & 3) * 16;
        const float* wp = watt + ((size_t)h * DD + r) * DD + c0;
        #pragma unroll
        for (int i = 0; i < 16; ++i) {
            const float f = wp[i] * WSC;
            __bf16 hv = (__bf16)f;
            Wh[c0 + i][r] = hv;                      // Wt_hi[e_out][d]
            Wl[c0 + i][r] = (__bf16)(f - (float)hv); // Wt_lo
        }
    }
    __syncthreads();

    // ---- Q = X_hi Wt_hi + X_hi Wt_lo + X_lo Wt_hi  (wave rows 32w..32w+32)
    v4f qacc[2][4] = {};
    #pragma unroll
    for (int kk = 0; kk < 2; ++kk) {
        v8bf xhf[2], xlf[2];
        #pragma unroll
        for (int mr = 0; mr < 2; ++mr) {
            xhf[mr] = *(const v8bf*)&KV0[w * 32 + mr * 16 + l15][kk * 32 + quad * 8];
            xlf[mr] = *(const v8bf*)&KV1[w * 32 + mr * 16 + l15][kk * 32 + quad * 8];
        }
        #pragma unroll
        for (int ns = 0; ns < 4; ++ns) {
            v8bf wh = *(const v8bf*)&Wh[ns * 16 + l15][kk * 32 + quad * 8];
            v8bf wl = *(const v8bf*)&Wl[ns * 16 + l15][kk * 32 + quad * 8];
            #pragma unroll
            for (int mr = 0; mr < 2; ++mr) {
                qacc[mr][ns] = MFMA16(xlf[mr], wh, qacc[mr][ns]);
                qacc[mr][ns] = MFMA16(xhf[mr], wl, qacc[mr][ns]);
                qacc[mr][ns] = MFMA16(xhf[mr], wh, qacc[mr][ns]);
            }
        }
    }
    __syncthreads();  // all waves done reading X/W regions

    // write Q hi/lo (C-layout scatter, wave-local rows), reload as frags
    #pragma unroll
    for (int mr = 0; mr < 2; ++mr)
        #pragma unroll
        for (int ns = 0; ns < 4; ++ns)
            #pragma unroll
            for (int r = 0; r < 4; ++r) {
                const float f = qacc[mr][ns][r];
                __bf16 hv = (__bf16)f;
                KV0[w * 32 + mr * 16 + quad * 4 + r][ns * 16 + l15] = hv;
                KV1[w * 32 + mr * 16 + quad * 4 + r][ns * 16 + l15] = (__bf16)(f - (float)hv);
            }
    v8bf qh[2][2], ql[2][2];
    #pragma unroll
    for (int mr = 0; mr < 2; ++mr)
        #pragma unroll
        for (int kk = 0; kk < 2; ++kk) {
            qh[mr][kk] = *(const v8bf*)&KV0[w * 32 + mr * 16 + l15][kk * 32 + quad * 8];
            ql[mr][kk] = *(const v8bf*)&KV1[w * 32 + mr * 16 + l15][kk * 32 + quad * 8];
        }
    __syncthreads();  // Q reloads done before staging overwrites KV0/KV1

    v4f oacc[2][4] = {};
    v4f lacc[2] = {};
    v4s ones;
    #pragma unroll
    for (int j = 0; j < 4; ++j) ones[j] = (short)0x3F80;  // bf16 1.0

    const __bf16* kb = xh + (size_t)b * TT * EE + h * DD;
    const __bf16* vb = vxT + ((size_t)(b * HH + h)) * DD * TT;
    const int kr = tid >> 2, kc = (tid & 3) * 16;

    uint4 ak0, ak1, av0, av1, bk0, bk1, bv0, bv1;

    auto loadR = [&](int idx, uint4& k0, uint4& k1, uint4& v0, uint4& v1) {
        const int s0 = idx * 64;
        k0 = *(const uint4*)(kb + (size_t)(s0 + kr) * EE + kc);
        k1 = *(const uint4*)(kb + (size_t)(s0 + kr) * EE + kc + 8);
        v0 = *(const uint4*)(vb + (size_t)kr * TT + s0 + kc);
        v1 = *(const uint4*)(vb + (size_t)kr * TT + s0 + kc + 8);
    };
    auto writeL = [&](__bf16 (*buf)[LDP], const uint4& k0, const uint4& k1,
                      const uint4& v0, const uint4& v1) {
        *(uint4*)&buf[kr][kc] = k0;
        *(uint4*)&buf[kr][kc + 8] = k1;
        *(uint4*)&buf[64 + kr][kc] = v0;
        *(uint4*)&buf[64 + kr][kc + 8] = v1;
    };
    auto computeT = [&](__bf16 (*buf)[LDP]) {
        // S^T = K (Q_hi + Q_lo)^T ; K rows 0-63 of buf
        v4f sacc[2][4] = {};
        #pragma unroll
        for (int kk = 0; kk < 2; ++kk)
            #pragma unroll
            for (int ss = 0; ss < 4; ++ss) {
                v8bf kf = *(const v8bf*)&buf[ss * 16 + l15][kk * 32 + quad * 8];
                #pragma unroll
                for (int mr = 0; mr < 2; ++mr) {
                    sacc[mr][ss] = MFMA16(kf, ql[mr][kk], sacc[mr][ss]);
                    sacc[mr][ss] = MFMA16(kf, qh[mr][kk], sacc[mr][ss]);
                }
            }
        // p = exp2(s) (log2e pre-folded); l via ones-MFMA
        v4s pa[2][4];
        #pragma unroll
        for (int mr = 0; mr < 2; ++mr)
            #pragma unroll
            for (int ss = 0; ss < 4; ++ss) {
                v4bf pb;
                #pragma unroll
                for (int r = 0; r < 4; ++r)
                    pb[r] = (__bf16)__builtin_amdgcn_exp2f(sacc[mr][ss][r]);
                union { v4bf b; v4s s; } u;
                u.b = pb;
                pa[mr][ss] = u.s;
                lacc[mr] = MFMA16K16(pa[mr][ss], ones, lacc[mr]);
            }
        // O += P V ; V^T rows 64-127 of buf
        #pragma unroll
        for (int ss = 0; ss < 4; ++ss)
            #pragma unroll
            for (int ds = 0; ds < 4; ++ds) {
                v4s vf = *(const v4s*)&buf[64 + ds * 16 + l15][ss * 16 + quad * 4];
                #pragma unroll
                for (int mr = 0; mr < 2; ++mr)
                    oacc[mr][ds] = MFMA16K16(pa[mr][ss], vf, oacc[mr][ds]);
            }
    };

    // ---- pipelined main loop: 32 s-tiles, ONE barrier per tile ----
    loadR(0, ak0, ak1, av0, av1);
    writeL(KV0, ak0, ak1, av0, av1);
    __syncthreads();
    loadR(1, ak0, ak1, av0, av1);

    for (int it = 0; it < 32; it += 2) {
        // tile it from KV0; stage tile it+1 -> KV1; prefetch it+2
        loadR(it + 2 < 32 ? it + 2 : 31, bk0, bk1, bv0, bv1);
        computeT(KV0);
        writeL(KV1, ak0, ak1, av0, av1);
        __syncthreads();
        // tile it+1 from KV1; stage tile it+2 -> KV0; prefetch it+3
        loadR(it + 3 < 32 ? it + 3 : 31, ak0, ak1, av0, av1);
        computeT(KV1);
        writeL(KV0, bk0, bk1, bv0, bv1);
        __syncthreads();
    }

    // ---- epilogue: l already in oacc layout; store O/l ----
    #pragma unroll
    for (int mr = 0; mr < 2; ++mr) {
        float inv[4];
        #pragma unroll
        for (int r = 0; r < 4; ++r) inv[r] = 1.0f / lacc[mr][r];
        #pragma unroll
        for (int ds = 0; ds < 4; ++ds)
            #pragma unroll
            for (int r = 0; r < 4; ++r) {
                const float val = oacc[mr][ds][r] * inv[r];
                o[(size_t)(b * TT + t0 + w * 32 + mr * 16 + quad * 4 + r) * EE +
                  h * DD + ds * 16 + l15] = (__bf16)val;
            }
    }
}

// ---------------------------------------------------------------------------
extern "C" void kernel_launch(void* const* d_in, const int* in_sizes, int n_in,
                              void* d_out, int out_size, void* d_ws, size_t ws_size,
                              hipStream_t stream)
{
    const float* x     = (const float*)d_in[0];
    const float* watt  = (const float*)d_in[1];
    const float* wv_w  = (const float*)d_in[2];
    const float* wv_b  = (const float*)d_in[3];
    const float* out_w = (const float*)d_in[4];
    const float* out_b = (const float*)d_in[5];
    float* out = (float*)d_out;

    __bf16* xhi = (__bf16*)d_ws;                         // B*T*E
    __bf16* wvb = xhi + (size_t)BB * TT * EE;            // E*E
    __bf16* owb = wvb + (size_t)EE * EE;                 // E*E
    __bf16* vxT = owb + (size_t)EE * EE;                 // B*H*D*T
    __bf16* obf = vxT + (size_t)BB * HH * DD * TT;       // B*T*E

    const int M = BB * TT;  // 4096

    cast_all<<<3072, 256, 0, stream>>>(x, wv_w, out_w, xhi, wvb, owb);

    // vx = x @ wv_w^T + wv_b, written transposed bf16 as (B,H,D,T)
    gemm_bf16<1><<<(M / 128) * (EE / 128), 512, 0, stream>>>(
        xhi, wvb, wv_b, (void*)vxT, M, EE, EE);

    // fused bilinear attention -> obf (B,T,E) bf16
    attn_mfma<<<dim3(TT / 128, HH, BB), 256, 0, stream>>>(x, xhi, watt, vxT, obf);

    // out = o @ out_w^T + out_b (fp32 out)
    gemm_bf16<0><<<(M / 128) * (EE / 128), 512, 0, stream>>>(
        obf, owb, out_b, (void*)out, M, EE, EE);
}